// Round 14
// baseline (196.190 us; speedup 1.0000x reference)
//
#include <hip/hip_runtime.h>
#include <hip/hip_bf16.h>
#include <stdint.h>

#define M_TOK 8192
#define N_OUT 4096
#define K_IN  4096

#define BM 256
#define BN 128
#define BKB 64             // K-tile depth in BYTES (= 64 i8 elements)
#define NT (K_IN / BKB)    // 64 K-tiles

typedef __attribute__((ext_vector_type(4))) int i32x4;

#define AS1 __attribute__((address_space(1)))
#define AS3 __attribute__((address_space(3)))
#define GLOAD_LDS16(g, l) \
  __builtin_amdgcn_global_load_lds((AS1 void*)(g), (AS3 void*)(l), 16, 0, 0)

#define BAR()     __builtin_amdgcn_s_barrier()
#define WAITALL() asm volatile("s_waitcnt vmcnt(0) lgkmcnt(0)" ::: "memory")
#define VMCNT6()  asm volatile("s_waitcnt vmcnt(6)" ::: "memory")
#define PRIO(p)   __builtin_amdgcn_s_setprio(p)
#define MFMAI8(a, b, c) __builtin_amdgcn_mfma_i32_16x16x64_i8((a), (b), (c), 0, 0, 0)

// ---------------- prep: x fp32 -> i8 with per-row scale (RNE) ----------------
__global__ __launch_bounds__(256) void quant_x_i8(const float4* __restrict__ x,
                                                  int4* __restrict__ o,
                                                  float* __restrict__ scales) {
  const int row = blockIdx.x;
  const int t   = threadIdx.x;
  const float4* xr = x + (size_t)row * (K_IN / 4);
  float4 v[4];
  #pragma unroll
  for (int i = 0; i < 4; ++i) v[i] = xr[t * 4 + i];
  float m = 0.f;
  #pragma unroll
  for (int i = 0; i < 4; ++i)
    m = fmaxf(m, fmaxf(fmaxf(fabsf(v[i].x), fabsf(v[i].y)),
                       fmaxf(fabsf(v[i].z), fabsf(v[i].w))));
  #pragma unroll
  for (int off = 32; off; off >>= 1) m = fmaxf(m, __shfl_down(m, off));
  __shared__ float sm[4];
  if ((t & 63) == 0) sm[t >> 6] = m;
  __syncthreads();
  m = fmaxf(fmaxf(sm[0], sm[1]), fmaxf(sm[2], sm[3]));
  const float inv = m > 0.f ? 127.f / m : 0.f;
  if (t == 0) scales[row] = m > 0.f ? m / 127.f : 1.f;
  int q[4];
  #pragma unroll
  for (int i = 0; i < 4; ++i) {
    const int a0 = (int)rintf(v[i].x * inv);
    const int a1 = (int)rintf(v[i].y * inv);
    const int a2 = (int)rintf(v[i].z * inv);
    const int a3 = (int)rintf(v[i].w * inv);
    q[i] = (a0 & 255) | ((a1 & 255) << 8) | ((a2 & 255) << 16) | (a3 << 24);
  }
  o[(size_t)row * (K_IN / 16) + t] = make_int4(q[0], q[1], q[2], q[3]);
}

// ---------------- prep: W fp32 -> sign in i8 {-1, 0, +1} ----------------
__global__ __launch_bounds__(256) void sgn_w_i8(const float4* __restrict__ w,
                                                int4* __restrict__ o, int n16) {
  int i = blockIdx.x * blockDim.x + threadIdx.x;
  int stride = gridDim.x * blockDim.x;
  for (; i < n16; i += stride) {
    int q[4];
    #pragma unroll
    for (int j = 0; j < 4; ++j) {
      float4 v = w[i * 4 + j];
      const int a0 = v.x > 0.f ? 1 : (v.x < 0.f ? -1 : 0);
      const int a1 = v.y > 0.f ? 1 : (v.y < 0.f ? -1 : 0);
      const int a2 = v.z > 0.f ? 1 : (v.z < 0.f ? -1 : 0);
      const int a3 = v.w > 0.f ? 1 : (v.w < 0.f ? -1 : 0);
      q[j] = (a0 & 255) | ((a1 & 255) << 8) | ((a2 & 255) << 16) | (a3 << 24);
    }
    o[i] = make_int4(q[0], q[1], q[2], q[3]);
  }
}

// ======== 256x128 i8 GEMM, 2-3 blocks/CU = independent barrier domains ======
// C[t][o] = (x_q[t][:] . w_q[o][:]) * scale[t].  i32 accumulate (exact).
// Round-13 post-mortem: every 1-block/CU schedule gives per-CU time =
// matrix + LDS-port (SUM, no overlap) because all 8 waves share one barrier
// group -> CU-wide phase lockstep (port-burst then matrix-burst). Fix: keep
// the per-wave geometry IDENTICAL (128x64 out/wave -> same port bytes and
// matrix work per wave) but shrink the block to 4 waves / 48 KiB LDS so 2-3
// blocks co-reside per CU. Blocks run anti-phased: one block's MFMA window
// covers the other's read/stage window (m114 co-scheduling).
// Same verified r6/r7 1-barrier schedule per block:
//   R1 {12 ds_reads + 16 MFMA m0-3} / WAITALL+BAR / R2 {stage t+2 + 16 MFMA m4-7}
// 64B-row swizzle: slot' = lk ^ ((row>>1)&3) -> exactly 2 lanes/bank (free).
// Staging source uses the same involution (rule #21).
__global__ __launch_bounds__(256, 2) void bin_gemm_i8(const char* __restrict__ A,
                                                      const char* __restrict__ B,
                                                      const float* __restrict__ scales,
                                                      float* __restrict__ C) {
  __shared__ char lds[49152];   // 2 buf x (A 16KB + B 8KB)

  const int tid  = threadIdx.x;
  const int w    = tid >> 6;     // 0..3
  const int lane = tid & 63;
  const int lr   = lane & 15;    // fragment row/col
  const int lk   = lane >> 4;    // k-slot 0..3 (16 bytes each)
  const int wr   = w >> 1;       // wave row 0..1 (128 rows each)
  const int wc   = w & 1;        // wave col 0..1 (64 cols each)

  const int bm = blockIdx.x >> 5;     // M/256 = 32
  const int bn = blockIdx.x & 31;     // N/128 = 32

  const char* Ag = A + (size_t)bm * BM * K_IN;
  const char* Bg = B + (size_t)bn * BN * K_IN;

  // staging: linear LDS dest + inverse-swizzled global source.
  // chunk c (16B): row r = c>>2, slot s = c&3; src slot = s ^ ((r>>1)&3).
  // A: 1024 chunks (256 rows), 4 instr/wave; B: 512 chunks (128 rows), 2.
  const int ca0 = w * 256 + lane;                // A chunk base (j=0)
  const int cb0 = w * 128 + lane;                // B chunk base (j=0)
  size_t gA[4], gB[2];
  #pragma unroll
  for (int j = 0; j < 4; ++j) {
    const int c = ca0 + j * 64;
    const int r = c >> 2;
    gA[j] = (size_t)r * K_IN + (size_t)((((c & 3) ^ ((r >> 1) & 3))) << 4);
  }
  #pragma unroll
  for (int j = 0; j < 2; ++j) {
    const int c = cb0 + j * 64;
    const int r = c >> 2;
    gB[j] = (size_t)r * K_IN + (size_t)((((c & 3) ^ ((r >> 1) & 3))) << 4);
  }

  auto stage = [&](int tt) {
    const size_t koff = (size_t)tt * BKB;
    char* base = &lds[(tt & 1) * 24576];
    #pragma unroll
    for (int j = 0; j < 4; ++j)
      GLOAD_LDS16(Ag + gA[j] + koff, base + w * 4096 + j * 1024);
    #pragma unroll
    for (int j = 0; j < 2; ++j)
      GLOAD_LDS16(Bg + gB[j] + koff, base + 16384 + w * 2048 + j * 1024);
  };

  // fragment reads (swizzled): row*64 + ((lk ^ ((row>>1)&3))<<4);
  // row = base + lr with base multiple of 16 => (row>>1)&3 == (lr>>1)&3.
  const int kof   = (lk ^ ((lr >> 1) & 3)) << 4;
  const int a_row = (wr * 128 + lr) * 64;
  const int b_row = 16384 + (wc * 64 + lr) * 64;

  i32x4 acc[8][4];
  #pragma unroll
  for (int m = 0; m < 8; ++m)
    #pragma unroll
    for (int n = 0; n < 4; ++n) { i32x4 z = {0, 0, 0, 0}; acc[m][n] = z; }

  // prologue: stage tiles 0,1 (6 gloads each); retire tile 0 (6 newer left).
  stage(0);
  stage(1);
  VMCNT6();
  BAR();

  for (int t = 0; t < NT; ++t) {
    const char* L = &lds[(t & 1) * 24576];
    i32x4 aF[8], bF[4];

    // ===== R1: 12 reads + MFMA m0-3 x n0-3 =====
    #pragma unroll
    for (int m = 0; m < 8; ++m)
      aF[m] = *(const i32x4*)(L + a_row + m * 1024 + kof);
    #pragma unroll
    for (int n = 0; n < 4; ++n)
      bF[n] = *(const i32x4*)(L + b_row + n * 1024 + kof);
    PRIO(1);
    #pragma unroll
    for (int m = 0; m < 4; ++m)
      #pragma unroll
      for (int n = 0; n < 4; ++n)
        acc[m][n] = MFMAI8(aF[m], bF[n], acc[m][n]);
    PRIO(0);

    // ---- mid: own reads retired + stage(t+1) drained; barrier globalizes
    WAITALL();
    BAR();

    // ===== R2: stage t+2 into buf[t&1] (dead) + MFMA m4-7 x n0-3 =====
    if (t + 2 < NT) stage(t + 2);
    PRIO(1);
    #pragma unroll
    for (int m = 4; m < 8; ++m)
      #pragma unroll
      for (int n = 0; n < 4; ++n)
        acc[m][n] = MFMAI8(aF[m], bF[n], acc[m][n]);
    PRIO(0);
  }

  // epilogue: C/D layout col=lane&15, row=(lane>>4)*4+reg; y = acc * scale[row]
  const int grow0 = bm * BM + wr * 128;
  float scl[8][4];
  #pragma unroll
  for (int m = 0; m < 8; ++m)
    #pragma unroll
    for (int j = 0; j < 4; ++j)
      scl[m][j] = scales[grow0 + m * 16 + lk * 4 + j];

  float* Cp = C + (size_t)grow0 * N_OUT + bn * BN + wc * 64;
  #pragma unroll
  for (int m = 0; m < 8; ++m)
    #pragma unroll
    for (int n = 0; n < 4; ++n)
      #pragma unroll
      for (int j = 0; j < 4; ++j)
        Cp[(size_t)(m * 16 + lk * 4 + j) * N_OUT + n * 16 + lr] =
            (float)acc[m][n][j] * scl[m][j];
}

// ---------------- fallback (ws too small): fp32 LDS-tiled, correct but slow --
__global__ __launch_bounds__(256) void fb_gemm(const float* __restrict__ x,
                                               const float* __restrict__ W,
                                               float* __restrict__ y) {
  __shared__ float xs[32][33];
  __shared__ float ws[32][33];
  const int bx = blockIdx.x;
  const int by = blockIdx.y;
  const int tx = threadIdx.x & 31;
  const int ty = threadIdx.x >> 5;
  float acc[4] = {0.f, 0.f, 0.f, 0.f};
  for (int k0 = 0; k0 < K_IN; k0 += 32) {
    #pragma unroll
    for (int i = 0; i < 4; ++i) {
      int r = ty + i * 8;
      xs[r][tx] = x[(size_t)(by * 32 + r) * K_IN + k0 + tx];
      float wv = W[(size_t)(bx * 32 + r) * K_IN + k0 + tx];
      ws[r][tx] = wv > 0.f ? 1.f : (wv < 0.f ? -1.f : 0.f);
    }
    __syncthreads();
    #pragma unroll
    for (int i = 0; i < 4; ++i) {
      int r = ty + i * 8;
      float s = acc[i];
      #pragma unroll
      for (int k = 0; k < 32; ++k) s += xs[r][k] * ws[tx][k];
      acc[i] = s;
    }
    __syncthreads();
  }
  #pragma unroll
  for (int i = 0; i < 4; ++i)
    y[(size_t)(by * 32 + ty + i * 8) * N_OUT + bx * 32 + tx] = acc[i];
}

extern "C" void kernel_launch(void* const* d_in, const int* in_sizes, int n_in,
                              void* d_out, int out_size, void* d_ws, size_t ws_size,
                              hipStream_t stream) {
  const float* x = (const float*)d_in[0];   // [8192, 4096]
  const float* W = (const float*)d_in[1];   // [4096, 4096]
  float* y = (float*)d_out;                 // [8192, 4096]

  const size_t need = (size_t)M_TOK * K_IN + (size_t)N_OUT * K_IN
                    + (size_t)M_TOK * sizeof(float);
  if (ws_size >= need) {
    char*  xq = (char*)d_ws;
    char*  wq = xq + (size_t)M_TOK * K_IN;
    float* sc = (float*)(wq + (size_t)N_OUT * K_IN);
    quant_x_i8<<<M_TOK, 256, 0, stream>>>((const float4*)x, (int4*)xq, sc);
    sgn_w_i8<<<2048, 256, 0, stream>>>((const float4*)W, (int4*)wq,
                                       N_OUT * K_IN / 16);
    bin_gemm_i8<<<(M_TOK / BM) * (N_OUT / BN), 256, 0, stream>>>(xq, wq, sc, y);
  } else {
    dim3 g(N_OUT / 32, M_TOK / 32);
    fb_gemm<<<g, 256, 0, stream>>>(x, W, y);
  }
}

// Round 15
// 188.637 us; speedup vs baseline: 1.0400x; 1.0400x over previous
//
#include <hip/hip_runtime.h>
#include <hip/hip_bf16.h>
#include <stdint.h>

#define M_TOK 8192
#define N_OUT 4096
#define K_IN  4096

#define BM 256
#define BN 256
#define BKB 64             // K-tile depth in BYTES (= 64 i8 elements)
#define NT (K_IN / BKB)    // 64 K-tiles

typedef __attribute__((ext_vector_type(4))) int i32x4;

#define AS1 __attribute__((address_space(1)))
#define AS3 __attribute__((address_space(3)))
#define GLOAD_LDS16(g, l) \
  __builtin_amdgcn_global_load_lds((AS1 void*)(g), (AS3 void*)(l), 16, 0, 0)

#define BAR()     __builtin_amdgcn_s_barrier()
#define VMCNT4()  asm volatile("s_waitcnt vmcnt(4)" ::: "memory")
#define VMCNT0()  asm volatile("s_waitcnt vmcnt(0)" ::: "memory")
#define PRIO(p)   __builtin_amdgcn_s_setprio(p)
#define MFMAI8(a, b, c) __builtin_amdgcn_mfma_i32_16x16x64_i8((a), (b), (c), 0, 0, 0)

// ---------------- prep: x fp32 -> i8 with per-row scale (RNE) ----------------
__global__ __launch_bounds__(256) void quant_x_i8(const float4* __restrict__ x,
                                                  int4* __restrict__ o,
                                                  float* __restrict__ scales) {
  const int row = blockIdx.x;
  const int t   = threadIdx.x;
  const float4* xr = x + (size_t)row * (K_IN / 4);
  float4 v[4];
  #pragma unroll
  for (int i = 0; i < 4; ++i) v[i] = xr[t * 4 + i];
  float m = 0.f;
  #pragma unroll
  for (int i = 0; i < 4; ++i)
    m = fmaxf(m, fmaxf(fmaxf(fabsf(v[i].x), fabsf(v[i].y)),
                       fmaxf(fabsf(v[i].z), fabsf(v[i].w))));
  #pragma unroll
  for (int off = 32; off; off >>= 1) m = fmaxf(m, __shfl_down(m, off));
  __shared__ float sm[4];
  if ((t & 63) == 0) sm[t >> 6] = m;
  __syncthreads();
  m = fmaxf(fmaxf(sm[0], sm[1]), fmaxf(sm[2], sm[3]));
  const float inv = m > 0.f ? 127.f / m : 0.f;
  if (t == 0) scales[row] = m > 0.f ? m / 127.f : 1.f;
  int q[4];
  #pragma unroll
  for (int i = 0; i < 4; ++i) {
    const int a0 = (int)rintf(v[i].x * inv);
    const int a1 = (int)rintf(v[i].y * inv);
    const int a2 = (int)rintf(v[i].z * inv);
    const int a3 = (int)rintf(v[i].w * inv);
    q[i] = (a0 & 255) | ((a1 & 255) << 8) | ((a2 & 255) << 16) | (a3 << 24);
  }
  o[(size_t)row * (K_IN / 16) + t] = make_int4(q[0], q[1], q[2], q[3]);
}

// ---------------- prep: W fp32 -> sign in i8 {-1, 0, +1} ----------------
__global__ __launch_bounds__(256) void sgn_w_i8(const float4* __restrict__ w,
                                                int4* __restrict__ o, int n16) {
  int i = blockIdx.x * blockDim.x + threadIdx.x;
  int stride = gridDim.x * blockDim.x;
  for (; i < n16; i += stride) {
    int q[4];
    #pragma unroll
    for (int j = 0; j < 4; ++j) {
      float4 v = w[i * 4 + j];
      const int a0 = v.x > 0.f ? 1 : (v.x < 0.f ? -1 : 0);
      const int a1 = v.y > 0.f ? 1 : (v.y < 0.f ? -1 : 0);
      const int a2 = v.z > 0.f ? 1 : (v.z < 0.f ? -1 : 0);
      const int a3 = v.w > 0.f ? 1 : (v.w < 0.f ? -1 : 0);
      q[j] = (a0 & 255) | ((a1 & 255) << 8) | ((a2 & 255) << 16) | (a3 << 24);
    }
    o[i] = make_int4(q[0], q[1], q[2], q[3]);
  }
}

// ======== 256x256 i8 GEMM, TRIPLE-buffered LDS, no mid-tile drain ========
// C[t][o] = (x_q[t][:] . w_q[o][:]) * scale[t].  i32 accumulate (exact).
// Round-14 post-mortem: every double-buffered schedule needs a mid-tile
// WAITALL (vmcnt0+lgkm0) before staging into the half-dead buffer — that
// drain serializes port and matrix once per tile (observed = sum of both).
// Triple buffer (BKB=64 -> 32 KB/tile x 3 = 96 KiB) removes it:
//   tile t: stage(t+2) -> buf[(t+2)%3] at TOP (that buffer's last reads were
//           in tile t-1; each read was consumed by an MFMA before t-1's end
//           barrier => lgkm-retired; barrier globalizes => free, no drain);
//           12 ds_reads (buf[t%3]) + 32 MFMA, compiler-interleaved;
//           vmcnt(4) [retires stage(t+1) issued a full tile ago; keeps
//           stage(t+2) in flight] + ONE barrier. No lgkm0/vmcnt0 in loop.
// 8 waves (2Mx4N), per-wave 128x64 out. 64B-row swizzle (r14-verified,
// 0 conflicts): frag slot = lk ^ ((row>>1)&3); staging src same involution.
__global__ __launch_bounds__(512, 2) void bin_gemm_i8(const char* __restrict__ A,
                                                      const char* __restrict__ B,
                                                      const float* __restrict__ scales,
                                                      float* __restrict__ C) {
  __shared__ char lds[98304];   // 3 buf x (A 16KB + B 16KB)

  const int tid  = threadIdx.x;
  const int w    = tid >> 6;     // 0..7
  const int lane = tid & 63;
  const int lr   = lane & 15;    // fragment row/col
  const int lk   = lane >> 4;    // k-slot 0..3 (16 bytes each)
  const int wr   = w >> 2;       // wave row 0..1 (128 rows each)
  const int wc   = w & 3;        // wave col 0..3 (64 cols each)

  const int bm = blockIdx.x >> 4;     // M/256 = 32
  const int bn = blockIdx.x & 15;     // N/256 = 16

  const char* Ag = A + (size_t)bm * BM * K_IN;
  const char* Bg = B + (size_t)bn * BN * K_IN;

  // staging: linear LDS dest + inverse-swizzled global source (rule #21).
  // chunk c (16B) of a 256-row x 64-B tile: row r = c>>2, slot s = c&3;
  // src slot = s ^ ((r>>1)&3).  A and B have identical chunk maps.
  const int c0 = w * 128 + lane;         // j=0
  const int c1 = c0 + 64;                // j=1
  const int ra0 = c0 >> 2, ra1 = c1 >> 2;
  const size_t g0 = (size_t)ra0 * K_IN
                  + (size_t)((((c0 & 3) ^ ((ra0 >> 1) & 3))) << 4);
  const size_t g1 = (size_t)ra1 * K_IN
                  + (size_t)((((c1 & 3) ^ ((ra1 >> 1) & 3))) << 4);
  const int ldsw = w * 2048;

  auto stage = [&](int tt, int bufoff) {
    const size_t koff = (size_t)tt * BKB;
    char* base = &lds[bufoff];
    GLOAD_LDS16(Ag + g0 + koff, base + ldsw);
    GLOAD_LDS16(Ag + g1 + koff, base + ldsw + 1024);
    GLOAD_LDS16(Bg + g0 + koff, base + 16384 + ldsw);
    GLOAD_LDS16(Bg + g1 + koff, base + 16384 + ldsw + 1024);
  };

  // fragment reads (swizzled): row*64 + ((lk ^ ((row>>1)&3))<<4); row's bits
  // 1..2 come only from lr (all row bases are multiples of 16).
  const int kof   = (lk ^ ((lr >> 1) & 3)) << 4;
  const int a_row = (wr * 128 + lr) * 64;
  const int b_row = 16384 + (wc * 64 + lr) * 64;

  i32x4 acc[8][4];
  #pragma unroll
  for (int m = 0; m < 8; ++m)
    #pragma unroll
    for (int n = 0; n < 4; ++n) { i32x4 z = {0, 0, 0, 0}; acc[m][n] = z; }

  // prologue: stage tiles 0,1 into buf0,buf1; retire tile 0 (4 newer remain).
  stage(0, 0);
  stage(1, 32768);
  VMCNT4();
  BAR();

  int oc = 0, on = 32768, op = 65536;   // cur, next, stage-target (= (t+2)%3)
  for (int t = 0; t < NT; ++t) {
    const char* L = &lds[oc];

    if (t + 2 < NT) stage(t + 2, op);

    i32x4 aF[8], bF[4];
    #pragma unroll
    for (int m = 0; m < 8; ++m)
      aF[m] = *(const i32x4*)(L + a_row + m * 1024 + kof);
    #pragma unroll
    for (int n = 0; n < 4; ++n)
      bF[n] = *(const i32x4*)(L + b_row + n * 1024 + kof);

    PRIO(1);
    #pragma unroll
    for (int m = 0; m < 8; ++m)
      #pragma unroll
      for (int n = 0; n < 4; ++n)
        acc[m][n] = MFMAI8(aF[m], bF[n], acc[m][n]);
    PRIO(0);

    // retire stage(t+1) (issued one full tile ago); keep stage(t+2) flying
    if (t < NT - 2) { VMCNT4(); } else { VMCNT0(); }
    BAR();

    const int tmp = oc; oc = on; on = op; op = tmp;
  }

  // epilogue: C/D layout col=lane&15, row=(lane>>4)*4+reg; y = acc * scale[row]
  const int grow0 = bm * BM + wr * 128;
  float scl[8][4];
  #pragma unroll
  for (int m = 0; m < 8; ++m)
    #pragma unroll
    for (int j = 0; j < 4; ++j)
      scl[m][j] = scales[grow0 + m * 16 + lk * 4 + j];

  float* Cp = C + (size_t)grow0 * N_OUT + bn * BN + wc * 64;
  #pragma unroll
  for (int m = 0; m < 8; ++m)
    #pragma unroll
    for (int n = 0; n < 4; ++n)
      #pragma unroll
      for (int j = 0; j < 4; ++j)
        Cp[(size_t)(m * 16 + lk * 4 + j) * N_OUT + n * 16 + lr] =
            (float)acc[m][n][j] * scl[m][j];
}

// ---------------- fallback (ws too small): fp32 LDS-tiled, correct but slow --
__global__ __launch_bounds__(256) void fb_gemm(const float* __restrict__ x,
                                               const float* __restrict__ W,
                                               float* __restrict__ y) {
  __shared__ float xs[32][33];
  __shared__ float ws[32][33];
  const int bx = blockIdx.x;
  const int by = blockIdx.y;
  const int tx = threadIdx.x & 31;
  const int ty = threadIdx.x >> 5;
  float acc[4] = {0.f, 0.f, 0.f, 0.f};
  for (int k0 = 0; k0 < K_IN; k0 += 32) {
    #pragma unroll
    for (int i = 0; i < 4; ++i) {
      int r = ty + i * 8;
      xs[r][tx] = x[(size_t)(by * 32 + r) * K_IN + k0 + tx];
      float wv = W[(size_t)(bx * 32 + r) * K_IN + k0 + tx];
      ws[r][tx] = wv > 0.f ? 1.f : (wv < 0.f ? -1.f : 0.f);
    }
    __syncthreads();
    #pragma unroll
    for (int i = 0; i < 4; ++i) {
      int r = ty + i * 8;
      float s = acc[i];
      #pragma unroll
      for (int k = 0; k < 32; ++k) s += xs[r][k] * ws[tx][k];
      acc[i] = s;
    }
    __syncthreads();
  }
  #pragma unroll
  for (int i = 0; i < 4; ++i)
    y[(size_t)(by * 32 + ty + i * 8) * N_OUT + bx * 32 + tx] = acc[i];
}

extern "C" void kernel_launch(void* const* d_in, const int* in_sizes, int n_in,
                              void* d_out, int out_size, void* d_ws, size_t ws_size,
                              hipStream_t stream) {
  const float* x = (const float*)d_in[0];   // [8192, 4096]
  const float* W = (const float*)d_in[1];   // [4096, 4096]
  float* y = (float*)d_out;                 // [8192, 4096]

  const size_t need = (size_t)M_TOK * K_IN + (size_t)N_OUT * K_IN
                    + (size_t)M_TOK * sizeof(float);
  if (ws_size >= need) {
    char*  xq = (char*)d_ws;
    char*  wq = xq + (size_t)M_TOK * K_IN;
    float* sc = (float*)(wq + (size_t)N_OUT * K_IN);
    quant_x_i8<<<M_TOK, 256, 0, stream>>>((const float4*)x, (int4*)xq, sc);
    sgn_w_i8<<<2048, 256, 0, stream>>>((const float4*)W, (int4*)wq,
                                       N_OUT * K_IN / 16);
    bin_gemm_i8<<<(M_TOK / BM) * (N_OUT / BN), 512, 0, stream>>>(xq, wq, sc, y);
  } else {
    dim3 g(N_OUT / 32, M_TOK / 32);
    fb_gemm<<<g, 256, 0, stream>>>(x, W, y);
  }
}